// Round 16
// baseline (55.513 us; speedup 1.0000x reference)
//
#include <hip/hip_runtime.h>

// MetaSR scale-4, single-launch producer/consumer MFMA GEMM.
// out[48][4096] = W[48][576] @ U[576][4096]; 16 distinct MLP inputs (exact
// in fp32); W bf16, K reordered k = tap*64 + c.
// Grid 768 (= conv blocks, XCD y-slice swizzled). Blocks 0..107 first
// compute the predw slice (R14 k_predw body), release-fence, bump flag.
// ALL blocks: issue feat loads + packs (predw-independent), THEN spin on
// flag (4B agent atomic only), acquire-fence, load afrags, 5 MFMAs, LDS
// reduce, store. Overlaps predw production with consumer cold-load latency;
// removes the serialized second dispatch ramp.

#define NOUT 1728

typedef short bf16x8 __attribute__((ext_vector_type(8)));
typedef float f32x4  __attribute__((ext_vector_type(4)));

__device__ inline unsigned short bf16r(float a) {
    const unsigned ua = __builtin_bit_cast(unsigned, a);
    return (unsigned short)((ua + 0x7FFFu + ((ua >> 16) & 1u)) >> 16);
}
__device__ inline unsigned bf16pack(float a, float b) {
    unsigned ua = __builtin_bit_cast(unsigned, a);
    unsigned ub = __builtin_bit_cast(unsigned, b);
    ua = (ua + 0x7FFFu + ((ua >> 16) & 1u)) >> 16;
    ub = (ub + 0x7FFFu + ((ub >> 16) & 1u)) >> 16;
    return ua | (ub << 16);
}

__global__ __launch_bounds__(256, 1) void k_all(
    const float* __restrict__ feat, const float* __restrict__ w1,
    const float* __restrict__ b1,   const float* __restrict__ w2,
    const float* __restrict__ b2,   unsigned short* predw16,
    unsigned* flag, float* __restrict__ out)
{
    __shared__ float h4[4][256];
    __shared__ float redA[1024];
    __shared__ f32x4 redB[192];

    const int tid = threadIdx.x;
    const int bid = blockIdx.x;

    // ------------- Phase A (blocks 0..107): predw16[m][tap*64+c] ----------
    if (bid < 108) {
        const int sg    = bid / 27;        // s-group (s = sg*4+si)
        const int chunk = bid - sg * 27;
        const int o_l   = tid & 63;
        const int q     = tid >> 6;        // K-quarter
        const int o     = chunk * 64 + o_l;

        {
            const float wa = w1[tid];
            const float wb = w1[256 + tid];
            const float wc = w1[512 + tid];
            const float bb = b1[tid];
            #pragma unroll
            for (int si = 0; si < 4; ++si) {
                h4[si][tid] = fmaxf(
                    fmaf(wa, (float)sg * 0.25f,
                    fmaf(wb, (float)si * 0.25f,
                    fmaf(wc, 0.25f, bb))), 0.0f);
            }
        }
        __syncthreads();

        const float* w2c = w2 + (q << 6) * NOUT + o;
        const float* hq0 = &h4[0][q << 6];
        const float* hq1 = &h4[1][q << 6];
        const float* hq2 = &h4[2][q << 6];
        const float* hq3 = &h4[3][q << 6];

        float a0 = 0.f, a1 = 0.f, a2 = 0.f, a3 = 0.f;
        #pragma unroll 16
        for (int j = 0; j < 64; ++j) {
            const float v = w2c[j * NOUT];
            a0 = fmaf(hq0[j], v, a0);
            a1 = fmaf(hq1[j], v, a1);
            a2 = fmaf(hq2[j], v, a2);
            a3 = fmaf(hq3[j], v, a3);
        }
        *(float4*)&redA[tid << 2] = make_float4(a0, a1, a2, a3);
        __syncthreads();

        {
            const int ol = tid >> 2;
            const int si = tid & 3;
            const int oo = chunk * 64 + ol;
            float a = redA[(0 * 64 + ol) * 4 + si]
                    + redA[(1 * 64 + ol) * 4 + si]
                    + redA[(2 * 64 + ol) * 4 + si]
                    + redA[(3 * 64 + ol) * 4 + si] + b2[oo];
            const int ct = oo / 3;
            const int k  = oo - ct * 3;
            const int c  = (ct * 7282) >> 16;   // ct/9 exact for ct<576
            const int tp = ct - c * 9;
            const int m  = ((sg << 2) + si) * 3 + k;
            predw16[m * 576 + tp * 64 + c] = bf16r(a);
        }
        __syncthreads();                        // all stores issued+drained
        if (tid == 0) {
            __builtin_amdgcn_fence(__ATOMIC_RELEASE, "agent");
            __hip_atomic_fetch_add(flag, 1u, __ATOMIC_RELEASE,
                                   __HIP_MEMORY_SCOPE_AGENT);
        }
    }

    // ------------- Phase B (all 768 blocks): MFMA conv --------------------
    const int lane = tid & 63;
    const int wv   = tid >> 6;            // K-split wave 0..3
    const int sx   = bid & 7;             // XCD (round-robin heuristic)
    const int u    = bid >> 3;            // 0..95
    const int mt   = u >> 5;              // m-tile 0..2
    const int v    = u & 31;
    const int y0   = (sx << 3) | (v >> 2);// y-slice per XCD
    const int x0   = (v & 3) << 4;

    const int lc = lane & 15;             // B col (cell) / A row (m)
    const int lk = lane >> 4;             // k subgroup 0..3

    int xadr[3]; float xmsk[3];
    #pragma unroll
    for (int d = 0; d < 3; ++d) {
        const int rx = x0 + lc + d - 1;
        xmsk[d] = ((unsigned)rx < 64u) ? 1.0f : 0.0f;
        xadr[d] = rx < 0 ? 0 : (rx > 63 ? 63 : rx);
    }
    int yadr[3]; float ymsk[3];
    #pragma unroll
    for (int d = 0; d < 3; ++d) {
        const int ry = y0 + d - 1;
        ymsk[d] = ((unsigned)ry < 64u) ? 1.0f : 0.0f;
        yadr[d] = (ry < 0 ? 0 : (ry > 63 ? 63 : ry)) << 6;
    }

    // feat loads + bf16 packs (predw-independent) BEFORE the spin
    bf16x8 bfr[5];
    #pragma unroll
    for (int i = 0; i < 5; ++i) {
        const int kk  = wv + (i << 2);              // 0..19
        const int kkc = kk > 17 ? 17 : kk;
        const float vld = (kk < 18) ? 1.0f : 0.0f;
        const int tap = kkc >> 1;
        const int dr  = (tap >= 6) ? 2 : (tap >= 3 ? 1 : 0);
        const int dc  = tap - dr * 3;
        const int c0  = ((kkc & 1) << 5) + (lk << 3);
        const float* fb = feat + (c0 << 12) + yadr[dr] + xadr[dc];
        const float  mk = ymsk[dr] * xmsk[dc] * vld;

        const float v0 = fb[0]       * mk;
        const float v1 = fb[1 << 12] * mk;
        const float v2 = fb[2 << 12] * mk;
        const float v3 = fb[3 << 12] * mk;
        const float v4 = fb[4 << 12] * mk;
        const float v5 = fb[5 << 12] * mk;
        const float v6 = fb[6 << 12] * mk;
        const float v7 = fb[7 << 12] * mk;

        uint4 bb;
        bb.x = bf16pack(v0, v1);
        bb.y = bf16pack(v2, v3);
        bb.z = bf16pack(v4, v5);
        bb.w = bf16pack(v6, v7);
        bfr[i] = __builtin_bit_cast(bf16x8, bb);
    }

    // wait for all 108 producer blocks (4B flag only)
    if (tid == 0) {
        while (__hip_atomic_load(flag, __ATOMIC_RELAXED,
                                 __HIP_MEMORY_SCOPE_AGENT) < 108u)
            __builtin_amdgcn_s_sleep(8);
    }
    __syncthreads();
    __builtin_amdgcn_fence(__ATOMIC_ACQUIRE, "agent");

    const unsigned short* arow = predw16 + (mt * 16 + lc) * 576 + (lk << 3);

    f32x4 acc = {0.0f, 0.0f, 0.0f, 0.0f};
    #pragma unroll
    for (int i = 0; i < 5; ++i) {
        const int kk  = wv + (i << 2);
        const int kkc = kk > 17 ? 17 : kk;
        const bf16x8 afrag = *(const bf16x8*)(arow + 32 * kkc);
        acc = __builtin_amdgcn_mfma_f32_16x16x32_bf16(afrag, bfr[i], acc,
                                                      0, 0, 0);
    }

    // 4-wave fp32 reduce (fixed order -> deterministic)
    if (wv > 0) redB[(wv - 1) * 64 + lane] = acc;
    __syncthreads();

    if (wv == 0) {
        #pragma unroll
        for (int q = 0; q < 3; ++q) {
            const f32x4 pv = redB[q * 64 + lane];
            acc[0] += pv[0]; acc[1] += pv[1]; acc[2] += pv[2]; acc[3] += pv[3];
        }
        #pragma unroll
        for (int r = 0; r < 4; ++r) {
            const int m = mt * 16 + (lk << 2) + r;
            const int s = (m * 171) >> 9;   // m/3 exact for m<48
            const int k = m - s * 3;
            const int y = (y0 << 2) + (s >> 2);
            const int x = ((x0 + lc) << 2) + (s & 3);
            out[k * 65536 + y * 256 + x] = acc[r];
        }
    }
}

extern "C" void kernel_launch(void* const* d_in, const int* in_sizes, int n_in,
                              void* d_out, int out_size, void* d_ws, size_t ws_size,
                              hipStream_t stream) {
    const float* feat = (const float*)d_in[0];
    const float* w1   = (const float*)d_in[1];
    const float* b1   = (const float*)d_in[2];
    const float* w2   = (const float*)d_in[3];
    const float* b2   = (const float*)d_in[4];
    float* out = (float*)d_out;

    unsigned short* predw16 = (unsigned short*)d_ws;          // 55296 B
    unsigned* flag = (unsigned*)((char*)d_ws + 55296);        // 4 B

    hipMemsetAsync(flag, 0, 4, stream);
    hipLaunchKernelGGL(k_all, dim3(768), dim3(256), 0, stream,
                       feat, w1, b1, w2, b2, predw16, flag, out);
}

// Round 17
// 16.909 us; speedup vs baseline: 3.2831x; 3.2831x over previous
//
#include <hip/hip_runtime.h>

// MetaSR scale-4 as MFMA GEMM, 2 launches (in-kernel sync measured 40-50us
// on this chip -> dead). Launch 1 (172 blocks x 256t): blocks 0..107 compute
// predw16[m=48][k=tap*64+c] (bf16); blocks 108..171 transpose feat NCHW ->
// NHWC featT[y][x][c]. Launch 2 (256 blocks x 768t): conv GEMM
// out[48][4096] = W @ unfold(feat): NHWC makes each lane's 8 k-elems
// consecutive -> 2 dwordx4 per kk (was 8 scalars at 4KB stride).
// 12 waves/CU, 1 block/CU; 4-wave K-split per mt + LDS reduce.

#define NOUT 1728

typedef short bf16x8 __attribute__((ext_vector_type(8)));
typedef float f32x4  __attribute__((ext_vector_type(4)));

__device__ inline unsigned short bf16r(float a) {
    const unsigned ua = __builtin_bit_cast(unsigned, a);
    return (unsigned short)((ua + 0x7FFFu + ((ua >> 16) & 1u)) >> 16);
}
__device__ inline unsigned bf16pack(float a, float b) {
    unsigned ua = __builtin_bit_cast(unsigned, a);
    unsigned ub = __builtin_bit_cast(unsigned, b);
    ua = (ua + 0x7FFFu + ((ua >> 16) & 1u)) >> 16;
    ub = (ub + 0x7FFFu + ((ub >> 16) & 1u)) >> 16;
    return ua | (ub << 16);
}

// ---------------- Launch 1: predw (108 blocks) + transpose (64 blocks) -----
__global__ __launch_bounds__(256) void k_prep(
    const float* __restrict__ w1, const float* __restrict__ b1,
    const float* __restrict__ w2, const float* __restrict__ b2,
    const float* __restrict__ feat,
    unsigned short* __restrict__ predw16, float* __restrict__ featT)
{
    __shared__ float h4[4][256];
    __shared__ float redA[1024];
    __shared__ float ftile[64][65];

    const int tid = threadIdx.x;
    const int bid = blockIdx.x;

    if (bid < 108) {
        const int sg    = bid / 27;        // s-group (s = sg*4+si)
        const int chunk = bid - sg * 27;
        const int o_l   = tid & 63;
        const int q     = tid >> 6;        // K-quarter
        const int o     = chunk * 64 + o_l;

        {
            const float wa = w1[tid];
            const float wb = w1[256 + tid];
            const float wc = w1[512 + tid];
            const float bb = b1[tid];
            #pragma unroll
            for (int si = 0; si < 4; ++si) {
                h4[si][tid] = fmaxf(
                    fmaf(wa, (float)sg * 0.25f,
                    fmaf(wb, (float)si * 0.25f,
                    fmaf(wc, 0.25f, bb))), 0.0f);
            }
        }
        __syncthreads();

        const float* w2c = w2 + (q << 6) * NOUT + o;
        const float* hq0 = &h4[0][q << 6];
        const float* hq1 = &h4[1][q << 6];
        const float* hq2 = &h4[2][q << 6];
        const float* hq3 = &h4[3][q << 6];

        float a0 = 0.f, a1 = 0.f, a2 = 0.f, a3 = 0.f;
        #pragma unroll 16
        for (int j = 0; j < 64; ++j) {
            const float v = w2c[j * NOUT];
            a0 = fmaf(hq0[j], v, a0);
            a1 = fmaf(hq1[j], v, a1);
            a2 = fmaf(hq2[j], v, a2);
            a3 = fmaf(hq3[j], v, a3);
        }
        *(float4*)&redA[tid << 2] = make_float4(a0, a1, a2, a3);
        __syncthreads();

        {
            const int ol = tid >> 2;
            const int si = tid & 3;
            const int oo = chunk * 64 + ol;
            float a = redA[(0 * 64 + ol) * 4 + si]
                    + redA[(1 * 64 + ol) * 4 + si]
                    + redA[(2 * 64 + ol) * 4 + si]
                    + redA[(3 * 64 + ol) * 4 + si] + b2[oo];
            const int ct = oo / 3;
            const int k  = oo - ct * 3;
            const int c  = (ct * 7282) >> 16;   // ct/9 exact for ct<576
            const int tp = ct - c * 9;
            const int m  = ((sg << 2) + si) * 3 + k;
            predw16[m * 576 + tp * 64 + c] = bf16r(a);
        }
    } else {
        // transpose one y-row: featT[(y*64+x)*64+c] = feat[c*4096+y*64+x]
        const int y  = bid - 108;          // 0..63
        const int cq = tid >> 6;           // 0..3
        const int xl = tid & 63;
        #pragma unroll
        for (int p = 0; p < 16; ++p) {
            const int c = (p << 2) + cq;
            ftile[c][xl] = feat[c * 4096 + y * 64 + xl];
        }
        __syncthreads();
        float* dst = featT + y * 4096;     // [x][c] block, 16 KB
        #pragma unroll
        for (int p = 0; p < 16; ++p) {
            const int x = (p << 2) + cq;
            dst[x * 64 + xl] = ftile[xl][x];
        }
    }
}

// ---------------- Launch 2: MFMA conv, NHWC, 768-thread blocks -------------
// grid 256: sx = bid&7 (XCD y-slice), u = bid>>3: y0 = sx*8+(u>>2),
// x0 = (u&3)*16. Block: wave = tid>>6 (mt = wave>>2, wv = wave&3).
__global__ __launch_bounds__(768, 1) void k_conv(
    const float* __restrict__ featT, const unsigned short* __restrict__ predw16,
    float* __restrict__ out)
{
    __shared__ f32x4 red[9 * 64];          // [mt][wv-1][lane]

    const int tid  = threadIdx.x;
    const int lane = tid & 63;
    const int wave = tid >> 6;             // 0..11
    const int mt   = wave >> 2;            // m-tile 0..2
    const int wv   = wave & 3;             // K-split 0..3
    const int bid  = blockIdx.x;
    const int sx   = bid & 7;
    const int u    = bid >> 3;
    const int y0   = (sx << 3) | (u >> 2);
    const int x0   = (u & 3) << 4;

    const int lc = lane & 15;              // B col (cell) / A row (m)
    const int lk = lane >> 4;              // k subgroup 0..3

    int xb[3]; float xmsk[3];
    #pragma unroll
    for (int d = 0; d < 3; ++d) {
        const int rx = x0 + lc + d - 1;
        xmsk[d] = ((unsigned)rx < 64u) ? 1.0f : 0.0f;
        xb[d] = (rx < 0 ? 0 : (rx > 63 ? 63 : rx)) << 6;
    }
    int yb[3]; float ymsk[3];
    #pragma unroll
    for (int d = 0; d < 3; ++d) {
        const int ry = y0 + d - 1;
        ymsk[d] = ((unsigned)ry < 64u) ? 1.0f : 0.0f;
        yb[d] = (ry < 0 ? 0 : (ry > 63 ? 63 : ry)) << 12;
    }

    const unsigned short* arow = predw16 + (mt * 16 + lc) * 576 + (lk << 3);

    f32x4 acc = {0.0f, 0.0f, 0.0f, 0.0f};

    #pragma unroll
    for (int i = 0; i < 5; ++i) {
        const int kk  = wv + (i << 2);               // 0..19
        const int kkc = kk > 17 ? 17 : kk;
        const float vld = (kk < 18) ? 1.0f : 0.0f;
        const int tap = kkc >> 1;
        const int dr  = (tap >= 6) ? 2 : (tap >= 3 ? 1 : 0);
        const int dc  = tap - dr * 3;
        const int c0  = ((kkc & 1) << 5) + (lk << 3); // 8 consecutive c
        const float* fb = featT + yb[dr] + xb[dc] + c0;
        const float  mk = ymsk[dr] * xmsk[dc] * vld;

        const float4 fa = *(const float4*)fb;
        const float4 fc = *(const float4*)(fb + 4);

        uint4 bb;
        bb.x = bf16pack(fa.x * mk, fa.y * mk);
        bb.y = bf16pack(fa.z * mk, fa.w * mk);
        bb.z = bf16pack(fc.x * mk, fc.y * mk);
        bb.w = bf16pack(fc.z * mk, fc.w * mk);
        const bf16x8 bfrag = __builtin_bit_cast(bf16x8, bb);
        const bf16x8 afrag = *(const bf16x8*)(arow + 32 * kkc);

        acc = __builtin_amdgcn_mfma_f32_16x16x32_bf16(afrag, bfrag, acc,
                                                      0, 0, 0);
    }

    // 4-wave fp32 reduce per mt (fixed order -> deterministic)
    if (wv > 0) red[(mt * 3 + (wv - 1)) * 64 + lane] = acc;
    __syncthreads();

    if (wv == 0) {
        #pragma unroll
        for (int q = 0; q < 3; ++q) {
            const f32x4 pv = red[(mt * 3 + q) * 64 + lane];
            acc[0] += pv[0]; acc[1] += pv[1]; acc[2] += pv[2]; acc[3] += pv[3];
        }
        #pragma unroll
        for (int r = 0; r < 4; ++r) {
            const int m = mt * 16 + (lk << 2) + r;
            const int s = (m * 171) >> 9;   // m/3 exact for m<48
            const int k = m - s * 3;
            const int y = (y0 << 2) + (s >> 2);
            const int x = ((x0 + lc) << 2) + (s & 3);
            out[k * 65536 + y * 256 + x] = acc[r];
        }
    }
}

extern "C" void kernel_launch(void* const* d_in, const int* in_sizes, int n_in,
                              void* d_out, int out_size, void* d_ws, size_t ws_size,
                              hipStream_t stream) {
    const float* feat = (const float*)d_in[0];
    const float* w1   = (const float*)d_in[1];
    const float* b1   = (const float*)d_in[2];
    const float* w2   = (const float*)d_in[3];
    const float* b2   = (const float*)d_in[4];
    float* out = (float*)d_out;

    unsigned short* predw16 = (unsigned short*)d_ws;          // 55296 B
    float* featT = (float*)((char*)d_ws + 57344);             // 1 MB

    hipLaunchKernelGGL(k_prep, dim3(172), dim3(256), 0, stream,
                       w1, b1, w2, b2, feat, predw16, featT);
    hipLaunchKernelGGL(k_conv, dim3(256), dim3(768), 0, stream,
                       featT, predw16, out);
}

// Round 18
// 16.817 us; speedup vs baseline: 3.3010x; 1.0054x over previous
//
#include <hip/hip_runtime.h>

// MetaSR scale-4 as MFMA GEMM, 2 launches (in-kernel cross-block sync
// measured 38-50us on this part -> dead; launch gaps measured ~1us in R2).
// Launch 1 (364 blocks): 0..107 predw16[m=48][k=tap*64+c] (bf16);
//   108..363 transpose feat NCHW -> NHWC featT[y][x][c] (coalesced both
//   sides, 1 tile each -- R16's 64-block serial transpose was the regress).
// Launch 2 (768 blocks = R13 best shape): conv GEMM via MFMA; NHWC makes
//   each lane's 8 k-elems two dwordx4 on one page (NCHW was 8 scalar loads
//   on 8 distinct 4KB pages -> cold-TLB thrash every replay, since the
//   harness's 268MB reset fill evicts L2+L3 between replays).

#define NOUT 1728

typedef short bf16x8 __attribute__((ext_vector_type(8)));
typedef float f32x4  __attribute__((ext_vector_type(4)));

__device__ inline unsigned short bf16r(float a) {
    const unsigned ua = __builtin_bit_cast(unsigned, a);
    return (unsigned short)((ua + 0x7FFFu + ((ua >> 16) & 1u)) >> 16);
}
__device__ inline unsigned bf16pack(float a, float b) {
    unsigned ua = __builtin_bit_cast(unsigned, a);
    unsigned ub = __builtin_bit_cast(unsigned, b);
    ua = (ua + 0x7FFFu + ((ua >> 16) & 1u)) >> 16;
    ub = (ub + 0x7FFFu + ((ub >> 16) & 1u)) >> 16;
    return ua | (ub << 16);
}

// ---------------- Launch 1: predw (108 blocks) + transpose (256 blocks) ----
__global__ __launch_bounds__(256) void k_prep(
    const float* __restrict__ w1, const float* __restrict__ b1,
    const float* __restrict__ w2, const float* __restrict__ b2,
    const float* __restrict__ feat,
    unsigned short* __restrict__ predw16, float* __restrict__ featT)
{
    __shared__ float h4[4][256];
    __shared__ float redA[1024];
    __shared__ float tile[16][65];

    const int tid = threadIdx.x;
    const int bid = blockIdx.x;

    if (bid < 108) {
        const int sg    = bid / 27;        // s-group (s = sg*4+si)
        const int chunk = bid - sg * 27;
        const int o_l   = tid & 63;
        const int q     = tid >> 6;        // K-quarter
        const int o     = chunk * 64 + o_l;

        {
            const float wa = w1[tid];
            const float wb = w1[256 + tid];
            const float wc = w1[512 + tid];
            const float bb = b1[tid];
            #pragma unroll
            for (int si = 0; si < 4; ++si) {
                h4[si][tid] = fmaxf(
                    fmaf(wa, (float)sg * 0.25f,
                    fmaf(wb, (float)si * 0.25f,
                    fmaf(wc, 0.25f, bb))), 0.0f);
            }
        }
        __syncthreads();

        const float* w2c = w2 + (q << 6) * NOUT + o;
        const float* hq0 = &h4[0][q << 6];
        const float* hq1 = &h4[1][q << 6];
        const float* hq2 = &h4[2][q << 6];
        const float* hq3 = &h4[3][q << 6];

        float a0 = 0.f, a1 = 0.f, a2 = 0.f, a3 = 0.f;
        #pragma unroll 16
        for (int j = 0; j < 64; ++j) {
            const float v = w2c[j * NOUT];
            a0 = fmaf(hq0[j], v, a0);
            a1 = fmaf(hq1[j], v, a1);
            a2 = fmaf(hq2[j], v, a2);
            a3 = fmaf(hq3[j], v, a3);
        }
        *(float4*)&redA[tid << 2] = make_float4(a0, a1, a2, a3);
        __syncthreads();

        {
            const int ol = tid >> 2;
            const int si = tid & 3;
            const int oo = chunk * 64 + ol;
            float a = redA[(0 * 64 + ol) * 4 + si]
                    + redA[(1 * 64 + ol) * 4 + si]
                    + redA[(2 * 64 + ol) * 4 + si]
                    + redA[(3 * 64 + ol) * 4 + si] + b2[oo];
            const int ct = oo / 3;
            const int k  = oo - ct * 3;
            const int c  = (ct * 7282) >> 16;   // ct/9 exact for ct<576
            const int tp = ct - c * 9;
            const int m  = ((sg << 2) + si) * 3 + k;
            predw16[m * 576 + tp * 64 + c] = bf16r(a);
        }
    } else {
        // NCHW -> NHWC: block = (cq, y); 16 channels x 64 x per block
        const int b  = bid - 108;          // 0..255
        const int y  = b & 63;
        const int cq = b >> 6;             // channel quarter (16 ch)
        // coalesced read: tid = cl*64 + x (4 passes of 4 channels)
        {
            const int cl = tid >> 6;       // 0..3
            const int x  = tid & 63;
            #pragma unroll
            for (int p = 0; p < 4; ++p)
                tile[p * 4 + cl][x] =
                    feat[((cq << 4) + p * 4 + cl) * 4096 + (y << 6) + x];
        }
        __syncthreads();
        // coalesced write: thread u -> float4 at [y][x=u>>2][cq*16+(u&3)*4]
        {
            const int x  = tid >> 2;
            const int c4 = (tid & 3) << 2;
            float4 v;
            v.x = tile[c4 + 0][x];
            v.y = tile[c4 + 1][x];
            v.z = tile[c4 + 2][x];
            v.w = tile[c4 + 3][x];
            *(float4*)&featT[(y << 12) + (x << 6) + (cq << 4) + c4] = v;
        }
    }
}

// ---------------- Launch 2: MFMA conv, NHWC, R13 grid shape ----------------
// grid 768: mt = bid>>8, nt = bid&255; block 256 = 4 waves, wave wv: kk=wv+4i
__global__ __launch_bounds__(256, 1) void k_conv(
    const float* __restrict__ featT, const unsigned short* __restrict__ predw16,
    float* __restrict__ out)
{
    __shared__ f32x4 red[3 * 64];          // partials of waves 1..3

    const int tid  = threadIdx.x;
    const int lane = tid & 63;
    const int wv   = tid >> 6;             // K-split wave 0..3
    const int bid  = blockIdx.x;
    const int mt   = bid >> 8;             // m-tile 0..2
    const int nt   = bid & 255;            // n-tile 0..255
    const int y0   = nt >> 2;
    const int x0   = (nt & 3) << 4;

    const int lc = lane & 15;              // B col (cell) / A row (m)
    const int lk = lane >> 4;              // k subgroup 0..3

    int xb[3]; float xmsk[3];
    #pragma unroll
    for (int d = 0; d < 3; ++d) {
        const int rx = x0 + lc + d - 1;
        xmsk[d] = ((unsigned)rx < 64u) ? 1.0f : 0.0f;
        xb[d] = (rx < 0 ? 0 : (rx > 63 ? 63 : rx)) << 6;
    }
    int yb[3]; float ymsk[3];
    #pragma unroll
    for (int d = 0; d < 3; ++d) {
        const int ry = y0 + d - 1;
        ymsk[d] = ((unsigned)ry < 64u) ? 1.0f : 0.0f;
        yb[d] = (ry < 0 ? 0 : (ry > 63 ? 63 : ry)) << 12;
    }

    const unsigned short* arow = predw16 + (mt * 16 + lc) * 576 + (lk << 3);

    f32x4 acc = {0.0f, 0.0f, 0.0f, 0.0f};

    #pragma unroll
    for (int i = 0; i < 5; ++i) {
        const int kk  = wv + (i << 2);               // 0..19
        const int kkc = kk > 17 ? 17 : kk;
        const float vld = (kk < 18) ? 1.0f : 0.0f;
        const int tap = kkc >> 1;
        const int dr  = (tap >= 6) ? 2 : (tap >= 3 ? 1 : 0);
        const int dc  = tap - dr * 3;
        const int c0  = ((kkc & 1) << 5) + (lk << 3); // 8 consecutive c
        const float* fb = featT + yb[dr] + xb[dc] + c0;
        const float  mk = ymsk[dr] * xmsk[dc] * vld;

        const float4 fa = *(const float4*)fb;
        const float4 fc = *(const float4*)(fb + 4);

        uint4 bb;
        bb.x = bf16pack(fa.x * mk, fa.y * mk);
        bb.y = bf16pack(fa.z * mk, fa.w * mk);
        bb.z = bf16pack(fc.x * mk, fc.y * mk);
        bb.w = bf16pack(fc.z * mk, fc.w * mk);
        const bf16x8 bfrag = __builtin_bit_cast(bf16x8, bb);
        const bf16x8 afrag = *(const bf16x8*)(arow + 32 * kkc);

        acc = __builtin_amdgcn_mfma_f32_16x16x32_bf16(afrag, bfrag, acc,
                                                      0, 0, 0);
    }

    // 4-wave fp32 reduce (fixed order -> deterministic)
    if (wv > 0) red[(wv - 1) * 64 + lane] = acc;
    __syncthreads();

    if (wv == 0) {
        #pragma unroll
        for (int q = 0; q < 3; ++q) {
            const f32x4 pv = red[q * 64 + lane];
            acc[0] += pv[0]; acc[1] += pv[1]; acc[2] += pv[2]; acc[3] += pv[3];
        }
        #pragma unroll
        for (int r = 0; r < 4; ++r) {
            const int m = mt * 16 + (lk << 2) + r;
            const int s = (m * 171) >> 9;   // m/3 exact for m<48
            const int k = m - s * 3;
            const int y = (y0 << 2) + (s >> 2);
            const int x = ((x0 + lc) << 2) + (s & 3);
            out[k * 65536 + y * 256 + x] = acc[r];
        }
    }
}

extern "C" void kernel_launch(void* const* d_in, const int* in_sizes, int n_in,
                              void* d_out, int out_size, void* d_ws, size_t ws_size,
                              hipStream_t stream) {
    const float* feat = (const float*)d_in[0];
    const float* w1   = (const float*)d_in[1];
    const float* b1   = (const float*)d_in[2];
    const float* w2   = (const float*)d_in[3];
    const float* b2   = (const float*)d_in[4];
    float* out = (float*)d_out;

    unsigned short* predw16 = (unsigned short*)d_ws;          // 55296 B
    float* featT = (float*)((char*)d_ws + 57344);             // 1 MB

    hipLaunchKernelGGL(k_prep, dim3(364), dim3(256), 0, stream,
                       w1, b1, w2, b2, feat, predw16, featT);
    hipLaunchKernelGGL(k_conv, dim3(768), dim3(256), 0, stream,
                       featT, predw16, out);
}

// Round 19
// 15.022 us; speedup vs baseline: 3.6954x; 1.1195x over previous
//
#include <hip/hip_runtime.h>

// MetaSR scale-4 as MFMA GEMM: out[48][4096] = W[48][576] @ U[576][4096].
// 16 distinct MLP inputs (exact in fp32) -> W rows m = s*3+k, K reordered
// k = tap*64 + c so B-fragments build in registers from L2/HBM (NCHW feat
// kept: R17 proved ws-intermediates pay cross-XCD dirty-line costs).
// R18 = R13 baseline with conv at 8-way K-split: 512-thr blocks, wave wv
// takes kk = wv + 8i -> 24 waves/CU (was 12), ~45 live VGPR (< 64 cap),
// 7KB LDS reduce, fixed order (deterministic, absmax-invariant).

#define NOUT 1728

typedef short bf16x8 __attribute__((ext_vector_type(8)));
typedef float f32x4  __attribute__((ext_vector_type(4)));

__device__ inline unsigned short bf16r(float a) {
    const unsigned ua = __builtin_bit_cast(unsigned, a);
    return (unsigned short)((ua + 0x7FFFu + ((ua >> 16) & 1u)) >> 16);
}
__device__ inline unsigned bf16pack(float a, float b) {
    unsigned ua = __builtin_bit_cast(unsigned, a);
    unsigned ub = __builtin_bit_cast(unsigned, b);
    ua = (ua + 0x7FFFu + ((ua >> 16) & 1u)) >> 16;
    ub = (ub + 0x7FFFu + ((ub >> 16) & 1u)) >> 16;
    return ua | (ub << 16);
}

// ---------------- Kernel 1: W as bf16, layout [m=48][k=tap*64+c] -----------
// grid 432 = 16 s * 27 chunks of 64 outputs; block 256 = 64 outputs * 4 Ksplit
__global__ __launch_bounds__(256) void k_predw(
    const float* __restrict__ w1, const float* __restrict__ b1,
    const float* __restrict__ w2, const float* __restrict__ b2,
    unsigned short* __restrict__ predw16)
{
    __shared__ float h[256];
    __shared__ float red[256];
    const int tid   = threadIdx.x;
    const int s     = blockIdx.x / 27;
    const int chunk = blockIdx.x - s * 27;

    const float rel0 = (float)(s >> 2) * 0.25f;
    const float rel1 = (float)(s & 3) * 0.25f;

    float pre = fmaf(w1[tid], rel0,
                fmaf(w1[256 + tid], rel1,
                fmaf(w1[512 + tid], 0.25f, b1[tid])));
    h[tid] = fmaxf(pre, 0.0f);
    __syncthreads();

    const int olocal = tid & 63;
    const int q      = tid >> 6;           // K-quarter
    const int o      = chunk * 64 + olocal;
    const float* w2c = w2 + q * 64 * NOUT + o;
    const float* hq  = h + q * 64;

    float acc = 0.0f;
    #pragma unroll 16
    for (int j = 0; j < 64; ++j)
        acc = fmaf(hq[j], w2c[j * NOUT], acc);
    red[tid] = acc;
    __syncthreads();

    if (tid < 64) {
        const int oo = chunk * 64 + tid;   // oo = ct*3 + k
        float a = red[tid] + red[tid + 64] + red[tid + 128] + red[tid + 192]
                + b2[oo];
        const int ct = oo / 3;
        const int k  = oo - ct * 3;
        const int c  = (ct * 7282) >> 16;  // ct/9 exact for ct<576
        const int tp = ct - c * 9;
        const int m  = s * 3 + k;
        predw16[m * 576 + tp * 64 + c] = bf16r(a);
    }
}

// ---------------- Kernel 2: MFMA conv, 8-wave K-split ----------------------
// grid 768: mt = bid>>8, nt = bid&255 (y0 = nt>>2, x0 = (nt&3)*16)
// block 512 = 8 waves; wave wv handles kk in {wv, wv+8, wv+16} (masked >17)
__global__ __launch_bounds__(512, 1) void k_conv(
    const float* __restrict__ feat, const unsigned short* __restrict__ predw16,
    float* __restrict__ out)
{
    __shared__ f32x4 red[7 * 64];          // partials of waves 1..7

    const int tid  = threadIdx.x;
    const int lane = tid & 63;
    const int wv   = tid >> 6;            // K-split wave 0..7
    const int bid  = blockIdx.x;
    const int mt   = bid >> 8;            // m-tile 0..2
    const int nt   = bid & 255;           // n-tile 0..255
    const int y0   = nt >> 2;
    const int x0   = (nt & 3) << 4;

    const int lc = lane & 15;             // B col (cell) / A row (m)
    const int lk = lane >> 4;             // k subgroup 0..3

    // per-lane clamped addr + masks for dc,dr in {0,1,2} (offset -1)
    int xadr[3]; float xmsk[3];
    #pragma unroll
    for (int d = 0; d < 3; ++d) {
        const int rx = x0 + lc + d - 1;
        xmsk[d] = ((unsigned)rx < 64u) ? 1.0f : 0.0f;
        xadr[d] = rx < 0 ? 0 : (rx > 63 ? 63 : rx);
    }
    int yadr[3]; float ymsk[3];
    #pragma unroll
    for (int d = 0; d < 3; ++d) {
        const int ry = y0 + d - 1;
        ymsk[d] = ((unsigned)ry < 64u) ? 1.0f : 0.0f;
        yadr[d] = (ry < 0 ? 0 : (ry > 63 ? 63 : ry)) << 6;
    }

    const unsigned short* arow = predw16 + (mt * 16 + lc) * 576 + (lk << 3);

    f32x4 acc = {0.0f, 0.0f, 0.0f, 0.0f};

    #pragma unroll
    for (int i = 0; i < 3; ++i) {
        const int kk  = wv + (i << 3);              // 0..23
        const int kkc = kk > 17 ? 17 : kk;          // clamp (addr-safe)
        const float vld = (kk < 18) ? 1.0f : 0.0f;  // mask instead of branch
        const int tap = kkc >> 1;
        const int dr  = (tap >= 6) ? 2 : (tap >= 3 ? 1 : 0);
        const int dc  = tap - dr * 3;
        const int c0  = ((kkc & 1) << 5) + (lk << 3);
        const float* fb = feat + (c0 << 12) + yadr[dr] + xadr[dc];
        const float  mk = ymsk[dr] * xmsk[dc] * vld;

        const float v0 = fb[0]       * mk;
        const float v1 = fb[1 << 12] * mk;
        const float v2 = fb[2 << 12] * mk;
        const float v3 = fb[3 << 12] * mk;
        const float v4 = fb[4 << 12] * mk;
        const float v5 = fb[5 << 12] * mk;
        const float v6 = fb[6 << 12] * mk;
        const float v7 = fb[7 << 12] * mk;

        uint4 bb;
        bb.x = bf16pack(v0, v1);
        bb.y = bf16pack(v2, v3);
        bb.z = bf16pack(v4, v5);
        bb.w = bf16pack(v6, v7);
        const bf16x8 bfrag = __builtin_bit_cast(bf16x8, bb);
        const bf16x8 afrag = *(const bf16x8*)(arow + 32 * kkc);

        acc = __builtin_amdgcn_mfma_f32_16x16x32_bf16(afrag, bfrag, acc,
                                                      0, 0, 0);
    }

    // 8-wave fp32 reduce (fixed order -> deterministic)
    if (wv > 0) red[(wv - 1) * 64 + lane] = acc;
    __syncthreads();

    if (wv == 0) {
        #pragma unroll
        for (int q = 0; q < 7; ++q) {
            const f32x4 v = red[q * 64 + lane];
            acc[0] += v[0]; acc[1] += v[1]; acc[2] += v[2]; acc[3] += v[3];
        }
        // D: col = lane&15 (cell), row = lk*4 + r (within m-tile)
        #pragma unroll
        for (int r = 0; r < 4; ++r) {
            const int m = mt * 16 + (lk << 2) + r;
            const int s = (m * 171) >> 9;  // m/3 exact for m<48
            const int k = m - s * 3;
            const int y = (y0 << 2) + (s >> 2);
            const int x = ((x0 + lc) << 2) + (s & 3);
            out[k * 65536 + y * 256 + x] = acc[r];
        }
    }
}

extern "C" void kernel_launch(void* const* d_in, const int* in_sizes, int n_in,
                              void* d_out, int out_size, void* d_ws, size_t ws_size,
                              hipStream_t stream) {
    const float* feat = (const float*)d_in[0];
    const float* w1   = (const float*)d_in[1];
    const float* b1   = (const float*)d_in[2];
    const float* w2   = (const float*)d_in[3];
    const float* b2   = (const float*)d_in[4];
    float* out = (float*)d_out;
    unsigned short* predw16 = (unsigned short*)d_ws;  // 48*576*2 = 55296 B

    hipLaunchKernelGGL(k_predw, dim3(432), dim3(256), 0, stream,
                       w1, b1, w2, b2, predw16);
    hipLaunchKernelGGL(k_conv, dim3(768), dim3(512), 0, stream,
                       feat, predw16, out);
}

// Round 20
// 14.103 us; speedup vs baseline: 3.9364x; 1.0652x over previous
//
#include <hip/hip_runtime.h>

// MetaSR scale-4 as MFMA GEMM: out[48][4096] = W[48][576] @ U[576][4096].
// 16 distinct MLP inputs (exact in fp32) -> W rows m = s*3+k, K reordered
// k = tap*64 + c so B-fragments build in registers from L2/HBM.
// FINAL (= R13, best measured 14.43us): conv K-split over 4 waves (kk mod 4),
// grid 768 = 3mt x 256nt -> 12 waves/CU, fp32 LDS reduce, wave0 writes.
// Measured-closed levers: waves/CU 24 (+0.6us), NHWC ws-intermediate
// (+2.4us, cross-XCD dirty lines), single-launch sync (+38-50us), predw
// load-count (null). Residual ~10us over warm-model = cold-replay floor
// (harness 268MB poison fills flush L2+L3 every replay) + 2 serialized
// dispatch ramps -- not addressable from kernel source (R12/R15 proofs).

#define NOUT 1728

typedef short bf16x8 __attribute__((ext_vector_type(8)));
typedef float f32x4  __attribute__((ext_vector_type(4)));

__device__ inline unsigned short bf16r(float a) {
    const unsigned ua = __builtin_bit_cast(unsigned, a);
    return (unsigned short)((ua + 0x7FFFu + ((ua >> 16) & 1u)) >> 16);
}
__device__ inline unsigned bf16pack(float a, float b) {
    unsigned ua = __builtin_bit_cast(unsigned, a);
    unsigned ub = __builtin_bit_cast(unsigned, b);
    ua = (ua + 0x7FFFu + ((ua >> 16) & 1u)) >> 16;
    ub = (ub + 0x7FFFu + ((ub >> 16) & 1u)) >> 16;
    return ua | (ub << 16);
}

// ---------------- Kernel 1: W as bf16, layout [m=48][k=tap*64+c] -----------
// grid 432 = 16 s * 27 chunks of 64 outputs; block 256 = 64 outputs * 4 Ksplit
__global__ __launch_bounds__(256) void k_predw(
    const float* __restrict__ w1, const float* __restrict__ b1,
    const float* __restrict__ w2, const float* __restrict__ b2,
    unsigned short* __restrict__ predw16)
{
    __shared__ float h[256];
    __shared__ float red[256];
    const int tid   = threadIdx.x;
    const int s     = blockIdx.x / 27;
    const int chunk = blockIdx.x - s * 27;

    const float rel0 = (float)(s >> 2) * 0.25f;
    const float rel1 = (float)(s & 3) * 0.25f;

    float pre = fmaf(w1[tid], rel0,
                fmaf(w1[256 + tid], rel1,
                fmaf(w1[512 + tid], 0.25f, b1[tid])));
    h[tid] = fmaxf(pre, 0.0f);
    __syncthreads();

    const int olocal = tid & 63;
    const int q      = tid >> 6;           // K-quarter
    const int o      = chunk * 64 + olocal;
    const float* w2c = w2 + q * 64 * NOUT + o;
    const float* hq  = h + q * 64;

    float acc = 0.0f;
    #pragma unroll 16
    for (int j = 0; j < 64; ++j)
        acc = fmaf(hq[j], w2c[j * NOUT], acc);
    red[tid] = acc;
    __syncthreads();

    if (tid < 64) {
        const int oo = chunk * 64 + tid;   // oo = ct*3 + k
        float a = red[tid] + red[tid + 64] + red[tid + 128] + red[tid + 192]
                + b2[oo];
        const int ct = oo / 3;
        const int k  = oo - ct * 3;
        const int c  = (ct * 7282) >> 16;  // ct/9 exact for ct<576
        const int tp = ct - c * 9;
        const int m  = s * 3 + k;
        predw16[m * 576 + tp * 64 + c] = bf16r(a);
    }
}

// ---------------- Kernel 2: MFMA conv, 4-wave K-split ----------------------
// grid 768: mt = bid>>8, nt = bid&255 (y0 = nt>>2, x0 = (nt&3)*16)
// block 256 = 4 waves; wave w handles kk in {w, w+4, ...} of 18 k-steps
__global__ __launch_bounds__(256) void k_conv(
    const float* __restrict__ feat, const unsigned short* __restrict__ predw16,
    float* __restrict__ out)
{
    __shared__ f32x4 red[3 * 64];          // partials of waves 1..3

    const int tid  = threadIdx.x;
    const int lane = tid & 63;
    const int w    = tid >> 6;            // K-split wave 0..3
    const int bid  = blockIdx.x;
    const int mt   = bid >> 8;            // m-tile 0..2
    const int nt   = bid & 255;           // n-tile 0..255
    const int y0   = nt >> 2;
    const int x0   = (nt & 3) << 4;

    const int lc = lane & 15;             // B col (cell) / A row (m)
    const int lk = lane >> 4;             // k subgroup 0..3

    // per-lane clamped addr + masks for dc,dr in {0,1,2} (offset -1)
    int xadr[3]; float xmsk[3];
    #pragma unroll
    for (int d = 0; d < 3; ++d) {
        const int rx = x0 + lc + d - 1;
        xmsk[d] = ((unsigned)rx < 64u) ? 1.0f : 0.0f;
        xadr[d] = rx < 0 ? 0 : (rx > 63 ? 63 : rx);
    }
    int yadr[3]; float ymsk[3];
    #pragma unroll
    for (int d = 0; d < 3; ++d) {
        const int ry = y0 + d - 1;
        ymsk[d] = ((unsigned)ry < 64u) ? 1.0f : 0.0f;
        yadr[d] = (ry < 0 ? 0 : (ry > 63 ? 63 : ry)) << 6;
    }

    const unsigned short* arow = predw16 + (mt * 16 + lc) * 576 + (lk << 3);

    f32x4 acc = {0.0f, 0.0f, 0.0f, 0.0f};

    #pragma unroll
    for (int i = 0; i < 5; ++i) {
        const int kk = w + (i << 2);
        if (kk < 18) {                    // wave-uniform predicate
            const int tap = kk >> 1;
            const int dr  = (tap >= 6) ? 2 : (tap >= 3 ? 1 : 0);
            const int dc  = tap - dr * 3;
            const int c0  = ((kk & 1) << 5) + (lk << 3);
            const float* fb = feat + (c0 << 12) + yadr[dr] + xadr[dc];
            const float  mk = ymsk[dr] * xmsk[dc];

            const float v0 = fb[0]       * mk;
            const float v1 = fb[1 << 12] * mk;
            const float v2 = fb[2 << 12] * mk;
            const float v3 = fb[3 << 12] * mk;
            const float v4 = fb[4 << 12] * mk;
            const float v5 = fb[5 << 12] * mk;
            const float v6 = fb[6 << 12] * mk;
            const float v7 = fb[7 << 12] * mk;

            uint4 bb;
            bb.x = bf16pack(v0, v1);
            bb.y = bf16pack(v2, v3);
            bb.z = bf16pack(v4, v5);
            bb.w = bf16pack(v6, v7);
            const bf16x8 bfrag = __builtin_bit_cast(bf16x8, bb);
            const bf16x8 afrag = *(const bf16x8*)(arow + 32 * kk);

            acc = __builtin_amdgcn_mfma_f32_16x16x32_bf16(afrag, bfrag, acc,
                                                          0, 0, 0);
        }
    }

    // 4-wave fp32 reduce (fixed order -> deterministic)
    if (w > 0) red[(w - 1) * 64 + lane] = acc;
    __syncthreads();

    if (w == 0) {
        #pragma unroll
        for (int q = 0; q < 3; ++q) {
            const f32x4 v = red[q * 64 + lane];
            acc[0] += v[0]; acc[1] += v[1]; acc[2] += v[2]; acc[3] += v[3];
        }
        // D: col = lane&15 (cell), row = lk*4 + r (within m-tile)
        #pragma unroll
        for (int r = 0; r < 4; ++r) {
            const int m = mt * 16 + (lk << 2) + r;
            const int s = (m * 171) >> 9;  // m/3 exact for m<48
            const int k = m - s * 3;
            const int y = (y0 << 2) + (s >> 2);
            const int x = ((x0 + lc) << 2) + (s & 3);
            out[k * 65536 + y * 256 + x] = acc[r];
        }
    }
}

extern "C" void kernel_launch(void* const* d_in, const int* in_sizes, int n_in,
                              void* d_out, int out_size, void* d_ws, size_t ws_size,
                              hipStream_t stream) {
    const float* feat = (const float*)d_in[0];
    const float* w1   = (const float*)d_in[1];
    const float* b1   = (const float*)d_in[2];
    const float* w2   = (const float*)d_in[3];
    const float* b2   = (const float*)d_in[4];
    float* out = (float*)d_out;
    unsigned short* predw16 = (unsigned short*)d_ws;  // 48*576*2 = 55296 B

    hipLaunchKernelGGL(k_predw, dim3(432), dim3(256), 0, stream,
                       w1, b1, w2, b2, predw16);
    hipLaunchKernelGGL(k_conv, dim3(768), dim3(256), 0, stream,
                       feat, predw16, out);
}